// Round 15
// baseline (110.781 us; speedup 1.0000x reference)
//
#include <hip/hip_runtime.h>

#define FFT_N 1024
#define NBLK 4096       // 4 waves/block, 1 row/wave -> 16384 rows

typedef float    float4n __attribute__((ext_vector_type(4)));
typedef _Float16 half2n  __attribute__((ext_vector_type(2)));
typedef _Float16 half8n  __attribute__((ext_vector_type(8)));

__device__ __forceinline__ int br6(int x) { return (int)(__brev((unsigned)x) >> 26); }

__device__ __forceinline__ unsigned int f2key(float f) {
    unsigned int u = __float_as_uint(f);
    return (u & 0x80000000u) ? ~u : (u | 0x80000000u);
}
__device__ __forceinline__ float key2f(unsigned int k) {
    unsigned int u = (k & 0x80000000u) ? (k & 0x7FFFFFFFu) : ~k;
    return __uint_as_float(u);
}

__global__ void init_mm(unsigned int* mm) {
    mm[0] = 0xFFFFFFFFu;
    mm[1] = 0u;
}

// in-register 8-pt inverse DIF over reg index (natural in, bit-rev out)
__device__ __forceinline__ void dif8(float* Zr, float* Zi) {
    const float R = 0.70710678118654752f;
    float tr, ti;
    tr = Zr[0]-Zr[4]; ti = Zi[0]-Zi[4]; Zr[0]+=Zr[4]; Zi[0]+=Zi[4]; Zr[4]=tr;        Zi[4]=ti;
    tr = Zr[1]-Zr[5]; ti = Zi[1]-Zi[5]; Zr[1]+=Zr[5]; Zi[1]+=Zi[5]; Zr[5]=R*(tr-ti); Zi[5]=R*(tr+ti);
    tr = Zr[2]-Zr[6]; ti = Zi[2]-Zi[6]; Zr[2]+=Zr[6]; Zi[2]+=Zi[6]; Zr[6]=-ti;       Zi[6]=tr;
    tr = Zr[3]-Zr[7]; ti = Zi[3]-Zi[7]; Zr[3]+=Zr[7]; Zi[3]+=Zi[7]; Zr[7]=-R*(tr+ti);Zi[7]=R*(tr-ti);
    tr = Zr[0]-Zr[2]; ti = Zi[0]-Zi[2]; Zr[0]+=Zr[2]; Zi[0]+=Zi[2]; Zr[2]=tr;  Zi[2]=ti;
    tr = Zr[1]-Zr[3]; ti = Zi[1]-Zi[3]; Zr[1]+=Zr[3]; Zi[1]+=Zi[3]; Zr[3]=-ti; Zi[3]=tr;
    tr = Zr[4]-Zr[6]; ti = Zi[4]-Zi[6]; Zr[4]+=Zr[6]; Zi[4]+=Zi[6]; Zr[6]=tr;  Zi[6]=ti;
    tr = Zr[5]-Zr[7]; ti = Zi[5]-Zi[7]; Zr[5]+=Zr[7]; Zi[5]+=Zi[7]; Zr[7]=-ti; Zi[7]=tr;
    tr = Zr[0]-Zr[1]; ti = Zi[0]-Zi[1]; Zr[0]+=Zr[1]; Zi[0]+=Zi[1]; Zr[1]=tr; Zi[1]=ti;
    tr = Zr[2]-Zr[3]; ti = Zi[2]-Zi[3]; Zr[2]+=Zr[3]; Zi[2]+=Zi[3]; Zr[3]=tr; Zi[3]=ti;
    tr = Zr[4]-Zr[5]; ti = Zi[4]-Zi[5]; Zr[4]+=Zr[5]; Zi[4]+=Zi[5]; Zr[5]=tr; Zi[5]=ti;
    tr = Zr[6]-Zr[7]; ti = Zi[6]-Zi[7]; Zr[6]+=Zr[7]; Zi[6]+=Zi[7]; Zr[7]=tr; Zi[7]=ti;
}

// One row per wave; 3 sincos per row (R13 math, verified).
// MODE 0: f32 raw into out + partials.  MODE 1: fp16 raw into ws + partials.
// MODE 2: f32 raw into out + atomic min/max.
// launch_bounds(256, 8): 8 waves/EU -> 8 blocks/CU (VGPR budget 64; kernel uses ~56).
template <int MODE>
__global__ __launch_bounds__(256, 8) void hifft_rows(const float* __restrict__ x,
                                                     float* __restrict__ out,
                                                     _Float16* __restrict__ raw,
                                                     float* __restrict__ partials,
                                                     unsigned int* __restrict__ mm) {
    const int t    = threadIdx.x;
    const int lane = t & 63;
    const int wid  = t >> 6;
    const int row  = blockIdx.x * 4 + wid;    // 0 .. 16383
    const int b    = row >> 10;
    const int p    = row & 1023;
    const float* re = x + (((size_t)(b * 2)) * 1024 + p) * 1024;
    const float* im = re + (size_t)1024 * 1024;

    // ---- loads: u = c[8l .. 8l+7], pp = c[512+8l .. 512+8l+7]  (8x dwordx4) ----
    float ur[8], ui[8], pr[8], pi[8];
    {
        const float4n* a  = (const float4n*)(re + 8 * lane);
        const float4n* bq = (const float4n*)(re + 512 + 8 * lane);
        const float4n* c4 = (const float4n*)(im + 8 * lane);
        const float4n* d4 = (const float4n*)(im + 512 + 8 * lane);
        float4n v0 = a[0], v1 = a[1], w0 = bq[0], w1 = bq[1];
        float4n y0 = c4[0], y1 = c4[1], z0 = d4[0], z1 = d4[1];
        ur[0]=v0.x; ur[1]=v0.y; ur[2]=v0.z; ur[3]=v0.w;
        ur[4]=v1.x; ur[5]=v1.y; ur[6]=v1.z; ur[7]=v1.w;
        pr[0]=w0.x; pr[1]=w0.y; pr[2]=w0.z; pr[3]=w0.w;
        pr[4]=w1.x; pr[5]=w1.y; pr[6]=w1.z; pr[7]=w1.w;
        ui[0]=y0.x; ui[1]=y0.y; ui[2]=y0.z; ui[3]=y0.w;
        ui[4]=y1.x; ui[5]=y1.y; ui[6]=y1.z; ui[7]=y1.w;
        pi[0]=z0.x; pi[1]=z0.y; pi[2]=z0.z; pi[3]=z0.w;
        pi[4]=z1.x; pi[5]=z1.y; pi[6]=z1.z; pi[7]=z1.w;
    }

    // ---- pack twiddle: W^(8l+j) = W^(8l) * C_j, C_j = e^{2pi i j/1024} const ----
    constexpr float CJR[8] = { 1.0f, 0.99998117528260111f, 0.99992470183914450f,
                               0.99983058179582340f, 0.99969881869620425f,
                               0.99952941750109314f, 0.99932238458834954f,
                               0.99907772775264536f };
    constexpr float CJI[8] = { 0.0f, 0.0061358846491544753f, 0.012271538285719925f,
                               0.018406729905804820f, 0.024541228522912288f,
                               0.030674803176636626f, 0.036807222941358832f,
                               0.042938256934940820f };
    float s0, c0;   // W^(8l) = e^{i*pi*lane/64}
    __sincosf(4.90873852123405e-2f * (float)lane, &s0, &c0);

    // ---- pack Z[k] = A + i*W^k*B with shuffle-sourced mirrors ----
    float Zr[8], Zi[8];
    {
        const int srcd = (64 - lane) & 63;
        float q_r = __shfl(ur[0], srcd), q_i = __shfl(ui[0], srcd);
        float v_r = __shfl(pr[0], srcd), v_i = __shfl(pi[0], srcd);
        if (lane == 0) { q_r = pr[0]; q_i = pi[0]; v_r = ur[0]; v_i = ui[0]; }
        float Ar = pr[0] + ur[0] + q_r + v_r;
        float Ai = pi[0] + ui[0] - q_i - v_i;
        float Br = pr[0] - ur[0] + q_r - v_r;
        float Bi = pi[0] - ui[0] - q_i + v_i;
        Zr[0] = Ar - (c0 * Bi + s0 * Br);
        Zi[0] = Ai + (c0 * Br - s0 * Bi);
    }
    #pragma unroll
    for (int j = 1; j < 8; ++j) {
        float q_r = __shfl_xor(ur[8 - j], 63), q_i = __shfl_xor(ui[8 - j], 63);
        float v_r = __shfl_xor(pr[8 - j], 63), v_i = __shfl_xor(pi[8 - j], 63);
        float wc = c0 * CJR[j] - s0 * CJI[j];       // W^(8l+j)
        float ws = s0 * CJR[j] + c0 * CJI[j];
        float Ar = pr[j] + ur[j] + q_r + v_r;
        float Ai = pi[j] + ui[j] - q_i - v_i;
        float Br = pr[j] - ur[j] + q_r - v_r;
        float Bi = pi[j] - ui[j] - q_i + v_i;
        Zr[j] = Ar - (wc * Bi + ws * Br);
        Zi[j] = Ai + (wc * Br - ws * Bi);
    }

    // ---- 64-pt cross-lane inverse DFT (radix-2 DIF, natural in, bit-rev out);
    //      stage twiddle via exact squaring chain: W_{h/2} = +-(W_h)^2 ----
    float ws, wc;   // W_h = e^{i*pi*(lane mod h)/h}, start h=32
    __sincosf(9.817477042468103e-2f * (float)(lane & 31), &ws, &wc);
    #pragma unroll
    for (int st = 0; st < 5; ++st) {
        const int h = 32 >> st;
        const bool hi = (lane & h) != 0;
        const float sgn  = hi ? -1.0f : 1.0f;
        const float ewc  = hi ? wc : 1.0f;
        const float ews  = hi ? ws : 0.0f;
        #pragma unroll
        for (int r = 0; r < 8; ++r) {
            float prt = __shfl_xor(Zr[r], h);
            float pit = __shfl_xor(Zi[r], h);
            float t1 = fmaf(sgn, Zr[r], prt);
            float t2 = fmaf(sgn, Zi[r], pit);
            Zr[r] = t1 * ewc - t2 * ews;
            Zi[r] = t1 * ews + t2 * ewc;
        }
        if (st < 4) {   // advance chain: W_{h/2} = (W_h)^2 * (-1)^{lane & h/2}
            const float s2 = (lane & (h >> 1)) ? -1.0f : 1.0f;
            float nwc = s2 * (wc * wc - ws * ws);
            float nws = s2 * (2.0f * wc * ws);
            wc = nwc; ws = nws;
        }
    }
    {
        const float sgn = (lane & 1) ? -1.0f : 1.0f;
        #pragma unroll
        for (int r = 0; r < 8; ++r) {
            float prt = __shfl_xor(Zr[r], 1);
            float pit = __shfl_xor(Zi[r], 1);
            Zr[r] = fmaf(sgn, Zr[r], prt);
            Zi[r] = fmaf(sgn, Zi[r], pit);
        }
    }

    // ---- per-lane twiddle e^{+2pi i * r * n1 / 512} via recurrence ----
    const int n1 = br6(lane);
    float bs, bc;   // base = e^{2pi i n1/512}
    __sincosf(1.2271846303085129e-2f * (float)n1, &bs, &bc);
    {
        float twc = bc, tws = bs;
        #pragma unroll
        for (int r = 1; r < 8; ++r) {
            float xr = Zr[r], xi = Zi[r];
            Zr[r] = xr * twc - xi * tws;
            Zi[r] = xr * tws + xi * twc;
            if (r < 7) {
                float nwc = twc * bc - tws * bs;
                float nws = twc * bs + tws * bc;
                twc = nwc; tws = nws;
            }
        }
    }

    // ---- 8-pt inverse DFT over regs (bit-rev out: reg r -> n2 = BR3[r]) ----
    dif8(Zr, Zi);

    // ---- unpack + store: X[m], m = n1 + 64*n2; y[2m]=Re*SC, y[2m+1]=Im*SC ----
    constexpr int BR3_[8] = {0, 4, 2, 6, 1, 5, 3, 7};
    const float SC = 4.8828125e-4f;   // 1/2048
    float vmin = INFINITY, vmax = -INFINITY;
    if constexpr (MODE == 1) {
        // fp16 transient: min/max tracked on the ROUNDED values for exactness
        _Float16* rrow = raw + (size_t)row * FFT_N + 2 * n1;
        #pragma unroll
        for (int r = 0; r < 8; ++r) {
            half2n h;
            h.x = (_Float16)(Zr[r] * SC);
            h.y = (_Float16)(Zi[r] * SC);
            float ra = (float)h.x, rb = (float)h.y;
            vmin = fminf(vmin, fminf(ra, rb));
            vmax = fmaxf(vmax, fmaxf(ra, rb));
            *reinterpret_cast<half2n*>(rrow + 128 * BR3_[r]) = h;
        }
    } else {
        float* orow = out + (size_t)row * FFT_N + 2 * n1;
        #pragma unroll
        for (int r = 0; r < 8; ++r) {
            float a  = Zr[r] * SC;
            float bb = Zi[r] * SC;
            vmin = fminf(vmin, fminf(a, bb));
            vmax = fmaxf(vmax, fmaxf(a, bb));
            *reinterpret_cast<float2*>(orow + 128 * BR3_[r]) = make_float2(a, bb);
        }
    }

    // ---- min/max: wave butterfly, cross-wave via LDS, one write per block ----
    #pragma unroll
    for (int off = 32; off >= 1; off >>= 1) {
        vmin = fminf(vmin, __shfl_xor(vmin, off));
        vmax = fmaxf(vmax, __shfl_xor(vmax, off));
    }
    __shared__ float smn[4], smx[4];
    if ((t & 63) == 0) { smn[wid] = vmin; smx[wid] = vmax; }
    __syncthreads();
    if (t == 0) {
        float mn = fminf(fminf(smn[0], smn[1]), fminf(smn[2], smn[3]));
        float mx = fmaxf(fmaxf(smx[0], smx[1]), fmaxf(smx[2], smx[3]));
        if (MODE == 2) {
            atomicMin(&mm[0], f2key(mn));
            atomicMax(&mm[1], f2key(mx));
        } else {
            reinterpret_cast<float2*>(partials)[blockIdx.x] = make_float2(mn, mx);
        }
    }
}

// shared partial-reduction: 4096 float2 partials -> (MN, INV) in LDS
__device__ __forceinline__ void reduce_partials(const float* __restrict__ partials,
                                                float& MN, float& INV) {
    float mn = INFINITY, mx = -INFINITY;
    #pragma unroll
    for (int it = 0; it < NBLK / 256; ++it) {
        float2 v = reinterpret_cast<const float2*>(partials)[threadIdx.x + it * 256];
        mn = fminf(mn, v.x);
        mx = fmaxf(mx, v.y);
    }
    #pragma unroll
    for (int off = 32; off >= 1; off >>= 1) {
        mn = fminf(mn, __shfl_xor(mn, off));
        mx = fmaxf(mx, __shfl_xor(mx, off));
    }
    __shared__ float smn[4], smx[4], bmm[2];
    const int wid = threadIdx.x >> 6;
    if ((threadIdx.x & 63) == 0) { smn[wid] = mn; smx[wid] = mx; }
    __syncthreads();
    if (threadIdx.x == 0) {
        bmm[0] = fminf(fminf(smn[0], smn[1]), fminf(smn[2], smn[3]));
        bmm[1] = fmaxf(fmaxf(smx[0], smx[1]), fmaxf(smx[2], smx[3]));
    }
    __syncthreads();
    MN  = bmm[0];
    INV = 1.0f / (bmm[1] - MN);
}

// fp16 path: read raw halfs (L3-hot), write normalized f32 nontemporal
__global__ __launch_bounds__(256, 8) void normalize_h(float* __restrict__ out,
                                                      const _Float16* __restrict__ raw,
                                                      const float* __restrict__ partials,
                                                      int n8) {
    float MN, INV;
    reduce_partials(partials, MN, INV);

    const half8n* r8 = reinterpret_cast<const half8n*>(raw);
    float4n* o4 = reinterpret_cast<float4n*>(out);
    for (int i = blockIdx.x * blockDim.x + threadIdx.x; i < n8;
         i += gridDim.x * blockDim.x) {
        half8n h = r8[i];
        float4n v0, v1;
        v0.x = ((float)h[0] - MN) * INV;
        v0.y = ((float)h[1] - MN) * INV;
        v0.z = ((float)h[2] - MN) * INV;
        v0.w = ((float)h[3] - MN) * INV;
        v1.x = ((float)h[4] - MN) * INV;
        v1.y = ((float)h[5] - MN) * INV;
        v1.z = ((float)h[6] - MN) * INV;
        v1.w = ((float)h[7] - MN) * INV;
        __builtin_nontemporal_store(v0, &o4[2 * i]);
        __builtin_nontemporal_store(v1, &o4[2 * i + 1]);
    }
}

// f32 fallback: reduce partials + normalize out in place
__global__ __launch_bounds__(256) void normalize_r(float* __restrict__ out,
                                                   const float* __restrict__ partials,
                                                   int n4) {
    float MN, INV;
    reduce_partials(partials, MN, INV);

    float4n* o4 = reinterpret_cast<float4n*>(out);
    for (int i = blockIdx.x * blockDim.x + threadIdx.x; i < n4;
         i += gridDim.x * blockDim.x) {
        float4n v = o4[i];
        v.x = (v.x - MN) * INV;
        v.y = (v.y - MN) * INV;
        v.z = (v.z - MN) * INV;
        v.w = (v.w - MN) * INV;
        __builtin_nontemporal_store(v, &o4[i]);
    }
}

__global__ __launch_bounds__(256) void normalize_k(float* __restrict__ out,
                                                   const unsigned int* __restrict__ mm,
                                                   int n4) {
    const float mn  = key2f(mm[0]);
    const float inv = 1.0f / (key2f(mm[1]) - mn);
    float4n* o4 = reinterpret_cast<float4n*>(out);
    for (int i = blockIdx.x * blockDim.x + threadIdx.x; i < n4;
         i += gridDim.x * blockDim.x) {
        float4n v = o4[i];
        v.x = (v.x - mn) * inv;
        v.y = (v.y - mn) * inv;
        v.z = (v.z - mn) * inv;
        v.w = (v.w - mn) * inv;
        o4[i] = v;
    }
}

extern "C" void kernel_launch(void* const* d_in, const int* in_sizes, int n_in,
                              void* d_out, int out_size, void* d_ws, size_t ws_size,
                              hipStream_t stream) {
    const float* x = (const float*)d_in[0];
    float* out = (float*)d_out;
    const int n4 = out_size / 4;
    const int n8 = out_size / 8;
    const size_t RAWB = (size_t)out_size * sizeof(_Float16);   // 33.5 MB
    const size_t PARTB = (size_t)(2 * NBLK) * sizeof(float);   // 32 KB

    if (ws_size >= RAWB + PARTB) {
        // fp16 transient path
        _Float16* raw = (_Float16*)d_ws;
        float* partials = (float*)((char*)d_ws + RAWB);
        hipLaunchKernelGGL((hifft_rows<1>), dim3(NBLK), dim3(256), 0, stream,
                           x, out, raw, partials, nullptr);
        hipLaunchKernelGGL(normalize_h, dim3(2048), dim3(256), 0, stream,
                           out, raw, partials, n8);
    } else if (ws_size >= PARTB) {
        // proven f32 path (raw into out, normalize in place)
        float* partials = (float*)d_ws;
        hipLaunchKernelGGL((hifft_rows<0>), dim3(NBLK), dim3(256), 0, stream,
                           x, out, nullptr, partials, nullptr);
        hipLaunchKernelGGL(normalize_r, dim3(2048), dim3(256), 0, stream,
                           out, partials, n4);
    } else {
        unsigned int* mm = (unsigned int*)d_ws;
        hipLaunchKernelGGL(init_mm, dim3(1), dim3(1), 0, stream, mm);
        hipLaunchKernelGGL((hifft_rows<2>), dim3(NBLK), dim3(256), 0, stream,
                           x, out, nullptr, nullptr, mm);
        hipLaunchKernelGGL(normalize_k, dim3(2048), dim3(256), 0, stream,
                           out, mm, n4);
    }
}

// Round 16
// 86.765 us; speedup vs baseline: 1.2768x; 1.2768x over previous
//
#include <hip/hip_runtime.h>

#define FFT_N 1024
#define NBLK2 2048      // 4 waves/block, 2 rows/wave (sequential) -> 16384 rows

typedef float    float4n __attribute__((ext_vector_type(4)));
typedef _Float16 half2n  __attribute__((ext_vector_type(2)));
typedef _Float16 half8n  __attribute__((ext_vector_type(8)));

__device__ __forceinline__ int br6(int x) { return (int)(__brev((unsigned)x) >> 26); }

__device__ __forceinline__ unsigned int f2key(float f) {
    unsigned int u = __float_as_uint(f);
    return (u & 0x80000000u) ? ~u : (u | 0x80000000u);
}
__device__ __forceinline__ float key2f(unsigned int k) {
    unsigned int u = (k & 0x80000000u) ? (k & 0x7FFFFFFFu) : ~k;
    return __uint_as_float(u);
}

__global__ void init_mm(unsigned int* mm) {
    mm[0] = 0xFFFFFFFFu;
    mm[1] = 0u;
}

// in-register 8-pt inverse DIF over reg index (natural in, bit-rev out)
__device__ __forceinline__ void dif8(float* Zr, float* Zi) {
    const float R = 0.70710678118654752f;
    float tr, ti;
    tr = Zr[0]-Zr[4]; ti = Zi[0]-Zi[4]; Zr[0]+=Zr[4]; Zi[0]+=Zi[4]; Zr[4]=tr;        Zi[4]=ti;
    tr = Zr[1]-Zr[5]; ti = Zi[1]-Zi[5]; Zr[1]+=Zr[5]; Zi[1]+=Zi[5]; Zr[5]=R*(tr-ti); Zi[5]=R*(tr+ti);
    tr = Zr[2]-Zr[6]; ti = Zi[2]-Zi[6]; Zr[2]+=Zr[6]; Zi[2]+=Zi[6]; Zr[6]=-ti;       Zi[6]=tr;
    tr = Zr[3]-Zr[7]; ti = Zi[3]-Zi[7]; Zr[3]+=Zr[7]; Zi[3]+=Zi[7]; Zr[7]=-R*(tr+ti);Zi[7]=R*(tr-ti);
    tr = Zr[0]-Zr[2]; ti = Zi[0]-Zi[2]; Zr[0]+=Zr[2]; Zi[0]+=Zi[2]; Zr[2]=tr;  Zi[2]=ti;
    tr = Zr[1]-Zr[3]; ti = Zi[1]-Zi[3]; Zr[1]+=Zr[3]; Zi[1]+=Zi[3]; Zr[3]=-ti; Zi[3]=tr;
    tr = Zr[4]-Zr[6]; ti = Zi[4]-Zi[6]; Zr[4]+=Zr[6]; Zi[4]+=Zi[6]; Zr[6]=tr;  Zi[6]=ti;
    tr = Zr[5]-Zr[7]; ti = Zi[5]-Zi[7]; Zr[5]+=Zr[7]; Zi[5]+=Zi[7]; Zr[7]=-ti; Zi[7]=tr;
    tr = Zr[0]-Zr[1]; ti = Zi[0]-Zi[1]; Zr[0]+=Zr[1]; Zi[0]+=Zi[1]; Zr[1]=tr; Zi[1]=ti;
    tr = Zr[2]-Zr[3]; ti = Zi[2]-Zi[3]; Zr[2]+=Zr[3]; Zi[2]+=Zi[3]; Zr[3]=tr; Zi[3]=ti;
    tr = Zr[4]-Zr[5]; ti = Zi[4]-Zi[5]; Zr[4]+=Zr[5]; Zi[4]+=Zi[5]; Zr[5]=tr; Zi[5]=ti;
    tr = Zr[6]-Zr[7]; ti = Zi[6]-Zi[7]; Zr[6]+=Zr[7]; Zi[6]+=Zi[7]; Zr[7]=tr; Zi[7]=ti;
}

// Full R13-verified row transform for one row; updates vmin/vmax.
// Stores fp16 raw (MODE 1) or f32 (MODE 0/2).
template <int MODE>
__device__ __forceinline__ void do_row(const float* __restrict__ re,
                                       const float* __restrict__ im,
                                       float* __restrict__ orow_f32,
                                       _Float16* __restrict__ orow_f16,
                                       int lane, float& vmin, float& vmax) {
    // ---- loads: u = c[8l .. 8l+7], pp = c[512+8l .. 512+8l+7]  (8x dwordx4) ----
    float ur[8], ui[8], pr[8], pi[8];
    {
        const float4n* a  = (const float4n*)(re + 8 * lane);
        const float4n* bq = (const float4n*)(re + 512 + 8 * lane);
        const float4n* c4 = (const float4n*)(im + 8 * lane);
        const float4n* d4 = (const float4n*)(im + 512 + 8 * lane);
        float4n v0 = a[0], v1 = a[1], w0 = bq[0], w1 = bq[1];
        float4n y0 = c4[0], y1 = c4[1], z0 = d4[0], z1 = d4[1];
        ur[0]=v0.x; ur[1]=v0.y; ur[2]=v0.z; ur[3]=v0.w;
        ur[4]=v1.x; ur[5]=v1.y; ur[6]=v1.z; ur[7]=v1.w;
        pr[0]=w0.x; pr[1]=w0.y; pr[2]=w0.z; pr[3]=w0.w;
        pr[4]=w1.x; pr[5]=w1.y; pr[6]=w1.z; pr[7]=w1.w;
        ui[0]=y0.x; ui[1]=y0.y; ui[2]=y0.z; ui[3]=y0.w;
        ui[4]=y1.x; ui[5]=y1.y; ui[6]=y1.z; ui[7]=y1.w;
        pi[0]=z0.x; pi[1]=z0.y; pi[2]=z0.z; pi[3]=z0.w;
        pi[4]=z1.x; pi[5]=z1.y; pi[6]=z1.z; pi[7]=z1.w;
    }

    // ---- pack twiddle: W^(8l+j) = W^(8l) * C_j ----
    constexpr float CJR[8] = { 1.0f, 0.99998117528260111f, 0.99992470183914450f,
                               0.99983058179582340f, 0.99969881869620425f,
                               0.99952941750109314f, 0.99932238458834954f,
                               0.99907772775264536f };
    constexpr float CJI[8] = { 0.0f, 0.0061358846491544753f, 0.012271538285719925f,
                               0.018406729905804820f, 0.024541228522912288f,
                               0.030674803176636626f, 0.036807222941358832f,
                               0.042938256934940820f };
    float s0, c0;   // W^(8l) = e^{i*pi*lane/64}
    __sincosf(4.90873852123405e-2f * (float)lane, &s0, &c0);

    // ---- pack Z[k] = A + i*W^k*B with shuffle-sourced mirrors ----
    float Zr[8], Zi[8];
    {
        const int srcd = (64 - lane) & 63;
        float q_r = __shfl(ur[0], srcd), q_i = __shfl(ui[0], srcd);
        float v_r = __shfl(pr[0], srcd), v_i = __shfl(pi[0], srcd);
        if (lane == 0) { q_r = pr[0]; q_i = pi[0]; v_r = ur[0]; v_i = ui[0]; }
        float Ar = pr[0] + ur[0] + q_r + v_r;
        float Ai = pi[0] + ui[0] - q_i - v_i;
        float Br = pr[0] - ur[0] + q_r - v_r;
        float Bi = pi[0] - ui[0] - q_i + v_i;
        Zr[0] = Ar - (c0 * Bi + s0 * Br);
        Zi[0] = Ai + (c0 * Br - s0 * Bi);
    }
    #pragma unroll
    for (int j = 1; j < 8; ++j) {
        float q_r = __shfl_xor(ur[8 - j], 63), q_i = __shfl_xor(ui[8 - j], 63);
        float v_r = __shfl_xor(pr[8 - j], 63), v_i = __shfl_xor(pi[8 - j], 63);
        float wc = c0 * CJR[j] - s0 * CJI[j];
        float ws = s0 * CJR[j] + c0 * CJI[j];
        float Ar = pr[j] + ur[j] + q_r + v_r;
        float Ai = pi[j] + ui[j] - q_i - v_i;
        float Br = pr[j] - ur[j] + q_r - v_r;
        float Bi = pi[j] - ui[j] - q_i + v_i;
        Zr[j] = Ar - (wc * Bi + ws * Br);
        Zi[j] = Ai + (wc * Br - ws * Bi);
    }

    // ---- 64-pt cross-lane inverse DFT; stage twiddle via squaring chain ----
    float ws, wc;   // W_h = e^{i*pi*(lane mod h)/h}, start h=32
    __sincosf(9.817477042468103e-2f * (float)(lane & 31), &ws, &wc);
    #pragma unroll
    for (int st = 0; st < 5; ++st) {
        const int h = 32 >> st;
        const bool hi = (lane & h) != 0;
        const float sgn  = hi ? -1.0f : 1.0f;
        const float ewc  = hi ? wc : 1.0f;
        const float ews  = hi ? ws : 0.0f;
        #pragma unroll
        for (int r = 0; r < 8; ++r) {
            float prt = __shfl_xor(Zr[r], h);
            float pit = __shfl_xor(Zi[r], h);
            float t1 = fmaf(sgn, Zr[r], prt);
            float t2 = fmaf(sgn, Zi[r], pit);
            Zr[r] = t1 * ewc - t2 * ews;
            Zi[r] = t1 * ews + t2 * ewc;
        }
        if (st < 4) {
            const float s2 = (lane & (h >> 1)) ? -1.0f : 1.0f;
            float nwc = s2 * (wc * wc - ws * ws);
            float nws = s2 * (2.0f * wc * ws);
            wc = nwc; ws = nws;
        }
    }
    {
        const float sgn = (lane & 1) ? -1.0f : 1.0f;
        #pragma unroll
        for (int r = 0; r < 8; ++r) {
            float prt = __shfl_xor(Zr[r], 1);
            float pit = __shfl_xor(Zi[r], 1);
            Zr[r] = fmaf(sgn, Zr[r], prt);
            Zi[r] = fmaf(sgn, Zi[r], pit);
        }
    }

    // ---- per-lane twiddle e^{+2pi i * r * n1 / 512} via recurrence ----
    const int n1 = br6(lane);
    float bs, bc;
    __sincosf(1.2271846303085129e-2f * (float)n1, &bs, &bc);
    {
        float twc = bc, tws = bs;
        #pragma unroll
        for (int r = 1; r < 8; ++r) {
            float xr = Zr[r], xi = Zi[r];
            Zr[r] = xr * twc - xi * tws;
            Zi[r] = xr * tws + xi * twc;
            if (r < 7) {
                float nwc = twc * bc - tws * bs;
                float nws = twc * bs + tws * bc;
                twc = nwc; tws = nws;
            }
        }
    }

    dif8(Zr, Zi);

    // ---- unpack + store: X[m], m = n1 + 64*n2 ----
    constexpr int BR3_[8] = {0, 4, 2, 6, 1, 5, 3, 7};
    const float SC = 4.8828125e-4f;   // 1/2048
    if constexpr (MODE == 1) {
        _Float16* rrow = orow_f16 + 2 * n1;
        #pragma unroll
        for (int r = 0; r < 8; ++r) {
            half2n h;
            h.x = (_Float16)(Zr[r] * SC);
            h.y = (_Float16)(Zi[r] * SC);
            float ra = (float)h.x, rb = (float)h.y;
            vmin = fminf(vmin, fminf(ra, rb));
            vmax = fmaxf(vmax, fmaxf(ra, rb));
            *reinterpret_cast<half2n*>(rrow + 128 * BR3_[r]) = h;
        }
    } else {
        float* orow = orow_f32 + 2 * n1;
        #pragma unroll
        for (int r = 0; r < 8; ++r) {
            float a  = Zr[r] * SC;
            float bb = Zi[r] * SC;
            vmin = fminf(vmin, fminf(a, bb));
            vmax = fmaxf(vmax, fmaxf(a, bb));
            *reinterpret_cast<float2*>(orow + 128 * BR3_[r]) = make_float2(a, bb);
        }
    }
}

// 2 rows per wave, sequential (rolled loop -> R14 register pressure per iter).
template <int MODE>
__global__ __launch_bounds__(256, 4) void hifft_rows2(const float* __restrict__ x,
                                                      float* __restrict__ out,
                                                      _Float16* __restrict__ raw,
                                                      float* __restrict__ partials,
                                                      unsigned int* __restrict__ mm) {
    const int t    = threadIdx.x;
    const int lane = t & 63;
    const int wid  = t >> 6;
    const int wave = blockIdx.x * 4 + wid;    // 0 .. 8191
    float vmin = INFINITY, vmax = -INFINITY;

    #pragma unroll 1
    for (int rr = 0; rr < 2; ++rr) {
        const int row = wave * 2 + rr;        // 0 .. 16383
        const int b   = row >> 10;
        const int p   = row & 1023;
        const float* re = x + (((size_t)(b * 2)) * 1024 + p) * 1024;
        const float* im = re + (size_t)1024 * 1024;
        do_row<MODE>(re, im,
                     out + (size_t)row * FFT_N,
                     raw ? raw + (size_t)row * FFT_N : nullptr,
                     lane, vmin, vmax);
    }

    // ---- min/max: wave butterfly, cross-wave via LDS, one write per block ----
    #pragma unroll
    for (int off = 32; off >= 1; off >>= 1) {
        vmin = fminf(vmin, __shfl_xor(vmin, off));
        vmax = fmaxf(vmax, __shfl_xor(vmax, off));
    }
    __shared__ float smn[4], smx[4];
    if ((t & 63) == 0) { smn[wid] = vmin; smx[wid] = vmax; }
    __syncthreads();
    if (t == 0) {
        float mn = fminf(fminf(smn[0], smn[1]), fminf(smn[2], smn[3]));
        float mx = fmaxf(fmaxf(smx[0], smx[1]), fmaxf(smx[2], smx[3]));
        if (MODE == 2) {
            atomicMin(&mm[0], f2key(mn));
            atomicMax(&mm[1], f2key(mx));
        } else {
            reinterpret_cast<float2*>(partials)[blockIdx.x] = make_float2(mn, mx);
        }
    }
}

// shared partial-reduction: 2048 float2 partials -> (MN, INV)
__device__ __forceinline__ void reduce_partials(const float* __restrict__ partials,
                                                float& MN, float& INV) {
    float mn = INFINITY, mx = -INFINITY;
    #pragma unroll
    for (int it = 0; it < NBLK2 / 256; ++it) {
        float2 v = reinterpret_cast<const float2*>(partials)[threadIdx.x + it * 256];
        mn = fminf(mn, v.x);
        mx = fmaxf(mx, v.y);
    }
    #pragma unroll
    for (int off = 32; off >= 1; off >>= 1) {
        mn = fminf(mn, __shfl_xor(mn, off));
        mx = fmaxf(mx, __shfl_xor(mx, off));
    }
    __shared__ float smn[4], smx[4], bmm[2];
    const int wid = threadIdx.x >> 6;
    if ((threadIdx.x & 63) == 0) { smn[wid] = mn; smx[wid] = mx; }
    __syncthreads();
    if (threadIdx.x == 0) {
        bmm[0] = fminf(fminf(smn[0], smn[1]), fminf(smn[2], smn[3]));
        bmm[1] = fmaxf(fmaxf(smx[0], smx[1]), fmaxf(smx[2], smx[3]));
    }
    __syncthreads();
    MN  = bmm[0];
    INV = 1.0f / (bmm[1] - MN);
}

// fp16 path: read raw halfs (L3-hot), write normalized f32 nontemporal
__global__ __launch_bounds__(256) void normalize_h(float* __restrict__ out,
                                                   const _Float16* __restrict__ raw,
                                                   const float* __restrict__ partials,
                                                   int n8) {
    float MN, INV;
    reduce_partials(partials, MN, INV);

    const half8n* r8 = reinterpret_cast<const half8n*>(raw);
    float4n* o4 = reinterpret_cast<float4n*>(out);
    for (int i = blockIdx.x * blockDim.x + threadIdx.x; i < n8;
         i += gridDim.x * blockDim.x) {
        half8n h = r8[i];
        float4n v0, v1;
        v0.x = ((float)h[0] - MN) * INV;
        v0.y = ((float)h[1] - MN) * INV;
        v0.z = ((float)h[2] - MN) * INV;
        v0.w = ((float)h[3] - MN) * INV;
        v1.x = ((float)h[4] - MN) * INV;
        v1.y = ((float)h[5] - MN) * INV;
        v1.z = ((float)h[6] - MN) * INV;
        v1.w = ((float)h[7] - MN) * INV;
        __builtin_nontemporal_store(v0, &o4[2 * i]);
        __builtin_nontemporal_store(v1, &o4[2 * i + 1]);
    }
}

// f32 fallback: reduce partials + normalize out in place
__global__ __launch_bounds__(256) void normalize_r(float* __restrict__ out,
                                                   const float* __restrict__ partials,
                                                   int n4) {
    float MN, INV;
    reduce_partials(partials, MN, INV);

    float4n* o4 = reinterpret_cast<float4n*>(out);
    for (int i = blockIdx.x * blockDim.x + threadIdx.x; i < n4;
         i += gridDim.x * blockDim.x) {
        float4n v = o4[i];
        v.x = (v.x - MN) * INV;
        v.y = (v.y - MN) * INV;
        v.z = (v.z - MN) * INV;
        v.w = (v.w - MN) * INV;
        __builtin_nontemporal_store(v, &o4[i]);
    }
}

__global__ __launch_bounds__(256) void normalize_k(float* __restrict__ out,
                                                   const unsigned int* __restrict__ mm,
                                                   int n4) {
    const float mn  = key2f(mm[0]);
    const float inv = 1.0f / (key2f(mm[1]) - mn);
    float4n* o4 = reinterpret_cast<float4n*>(out);
    for (int i = blockIdx.x * blockDim.x + threadIdx.x; i < n4;
         i += gridDim.x * blockDim.x) {
        float4n v = o4[i];
        v.x = (v.x - mn) * inv;
        v.y = (v.y - mn) * inv;
        v.z = (v.z - mn) * inv;
        v.w = (v.w - mn) * inv;
        o4[i] = v;
    }
}

extern "C" void kernel_launch(void* const* d_in, const int* in_sizes, int n_in,
                              void* d_out, int out_size, void* d_ws, size_t ws_size,
                              hipStream_t stream) {
    const float* x = (const float*)d_in[0];
    float* out = (float*)d_out;
    const int n4 = out_size / 4;
    const int n8 = out_size / 8;
    const size_t RAWB = (size_t)out_size * sizeof(_Float16);   // 33.5 MB
    const size_t PARTB = (size_t)(2 * NBLK2) * sizeof(float);  // 16 KB

    if (ws_size >= RAWB + PARTB) {
        // fp16 transient path
        _Float16* raw = (_Float16*)d_ws;
        float* partials = (float*)((char*)d_ws + RAWB);
        hipLaunchKernelGGL((hifft_rows2<1>), dim3(NBLK2), dim3(256), 0, stream,
                           x, out, raw, partials, nullptr);
        hipLaunchKernelGGL(normalize_h, dim3(2048), dim3(256), 0, stream,
                           out, raw, partials, n8);
    } else if (ws_size >= PARTB) {
        // proven f32 path (raw into out, normalize in place)
        float* partials = (float*)d_ws;
        hipLaunchKernelGGL((hifft_rows2<0>), dim3(NBLK2), dim3(256), 0, stream,
                           x, out, nullptr, partials, nullptr);
        hipLaunchKernelGGL(normalize_r, dim3(2048), dim3(256), 0, stream,
                           out, partials, n4);
    } else {
        unsigned int* mm = (unsigned int*)d_ws;
        hipLaunchKernelGGL(init_mm, dim3(1), dim3(1), 0, stream, mm);
        hipLaunchKernelGGL((hifft_rows2<2>), dim3(NBLK2), dim3(256), 0, stream,
                           x, out, nullptr, nullptr, mm);
        hipLaunchKernelGGL(normalize_k, dim3(2048), dim3(256), 0, stream,
                           out, mm, n4);
    }
}

// Round 17
// 59.811 us; speedup vs baseline: 1.8522x; 1.4506x over previous
//
#include <hip/hip_runtime.h>

#define FFT_N 1024
#define NBLK 4096       // 4 waves/block, 1 row/wave -> 16384 rows

typedef float    float4n __attribute__((ext_vector_type(4)));
typedef _Float16 half2n  __attribute__((ext_vector_type(2)));
typedef _Float16 half8n  __attribute__((ext_vector_type(8)));

__device__ __forceinline__ int br6(int x) { return (int)(__brev((unsigned)x) >> 26); }

__device__ __forceinline__ unsigned int f2key(float f) {
    unsigned int u = __float_as_uint(f);
    return (u & 0x80000000u) ? ~u : (u | 0x80000000u);
}
__device__ __forceinline__ float key2f(unsigned int k) {
    unsigned int u = (k & 0x80000000u) ? (k & 0x7FFFFFFFu) : ~k;
    return __uint_as_float(u);
}

__global__ void init_mm(unsigned int* mm) {
    mm[0] = 0xFFFFFFFFu;
    mm[1] = 0u;
}

// in-register 8-pt inverse DIF over reg index (natural in, bit-rev out)
__device__ __forceinline__ void dif8(float* Zr, float* Zi) {
    const float R = 0.70710678118654752f;
    float tr, ti;
    tr = Zr[0]-Zr[4]; ti = Zi[0]-Zi[4]; Zr[0]+=Zr[4]; Zi[0]+=Zi[4]; Zr[4]=tr;        Zi[4]=ti;
    tr = Zr[1]-Zr[5]; ti = Zi[1]-Zi[5]; Zr[1]+=Zr[5]; Zi[1]+=Zi[5]; Zr[5]=R*(tr-ti); Zi[5]=R*(tr+ti);
    tr = Zr[2]-Zr[6]; ti = Zi[2]-Zi[6]; Zr[2]+=Zr[6]; Zi[2]+=Zi[6]; Zr[6]=-ti;       Zi[6]=tr;
    tr = Zr[3]-Zr[7]; ti = Zi[3]-Zi[7]; Zr[3]+=Zr[7]; Zi[3]+=Zi[7]; Zr[7]=-R*(tr+ti);Zi[7]=R*(tr-ti);
    tr = Zr[0]-Zr[2]; ti = Zi[0]-Zi[2]; Zr[0]+=Zr[2]; Zi[0]+=Zi[2]; Zr[2]=tr;  Zi[2]=ti;
    tr = Zr[1]-Zr[3]; ti = Zi[1]-Zi[3]; Zr[1]+=Zr[3]; Zi[1]+=Zi[3]; Zr[3]=-ti; Zi[3]=tr;
    tr = Zr[4]-Zr[6]; ti = Zi[4]-Zi[6]; Zr[4]+=Zr[6]; Zi[4]+=Zi[6]; Zr[6]=tr;  Zi[6]=ti;
    tr = Zr[5]-Zr[7]; ti = Zi[5]-Zi[7]; Zr[5]+=Zr[7]; Zi[5]+=Zi[7]; Zr[7]=-ti; Zi[7]=tr;
    tr = Zr[0]-Zr[1]; ti = Zi[0]-Zi[1]; Zr[0]+=Zr[1]; Zi[0]+=Zi[1]; Zr[1]=tr; Zi[1]=ti;
    tr = Zr[2]-Zr[3]; ti = Zi[2]-Zi[3]; Zr[2]+=Zr[3]; Zi[2]+=Zi[3]; Zr[3]=tr; Zi[3]=ti;
    tr = Zr[4]-Zr[5]; ti = Zi[4]-Zi[5]; Zr[4]+=Zr[5]; Zi[4]+=Zi[5]; Zr[5]=tr; Zi[5]=ti;
    tr = Zr[6]-Zr[7]; ti = Zi[6]-Zi[7]; Zr[6]+=Zr[7]; Zi[6]+=Zi[7]; Zr[7]=tr; Zi[7]=ti;
}

// One row per wave; 3 sincos per row (R13 math, verified).
// MODE 0: f32 raw into out + partials.  MODE 1: fp16 raw into ws + partials.
// MODE 2: f32 raw into out + atomic min/max.
template <int MODE>
__global__ __launch_bounds__(256, 4) void hifft_rows(const float* __restrict__ x,
                                                     float* __restrict__ out,
                                                     _Float16* __restrict__ raw,
                                                     float* __restrict__ partials,
                                                     unsigned int* __restrict__ mm) {
    const int t    = threadIdx.x;
    const int lane = t & 63;
    const int wid  = t >> 6;
    const int row  = blockIdx.x * 4 + wid;    // 0 .. 16383
    const int b    = row >> 10;
    const int p    = row & 1023;
    const float* re = x + (((size_t)(b * 2)) * 1024 + p) * 1024;
    const float* im = re + (size_t)1024 * 1024;

    // ---- loads: u = c[8l .. 8l+7], pp = c[512+8l .. 512+8l+7]  (8x dwordx4) ----
    float ur[8], ui[8], pr[8], pi[8];
    {
        const float4n* a  = (const float4n*)(re + 8 * lane);
        const float4n* bq = (const float4n*)(re + 512 + 8 * lane);
        const float4n* c4 = (const float4n*)(im + 8 * lane);
        const float4n* d4 = (const float4n*)(im + 512 + 8 * lane);
        float4n v0 = a[0], v1 = a[1], w0 = bq[0], w1 = bq[1];
        float4n y0 = c4[0], y1 = c4[1], z0 = d4[0], z1 = d4[1];
        ur[0]=v0.x; ur[1]=v0.y; ur[2]=v0.z; ur[3]=v0.w;
        ur[4]=v1.x; ur[5]=v1.y; ur[6]=v1.z; ur[7]=v1.w;
        pr[0]=w0.x; pr[1]=w0.y; pr[2]=w0.z; pr[3]=w0.w;
        pr[4]=w1.x; pr[5]=w1.y; pr[6]=w1.z; pr[7]=w1.w;
        ui[0]=y0.x; ui[1]=y0.y; ui[2]=y0.z; ui[3]=y0.w;
        ui[4]=y1.x; ui[5]=y1.y; ui[6]=y1.z; ui[7]=y1.w;
        pi[0]=z0.x; pi[1]=z0.y; pi[2]=z0.z; pi[3]=z0.w;
        pi[4]=z1.x; pi[5]=z1.y; pi[6]=z1.z; pi[7]=z1.w;
    }

    // ---- pack twiddle: W^(8l+j) = W^(8l) * C_j, C_j = e^{2pi i j/1024} const ----
    constexpr float CJR[8] = { 1.0f, 0.99998117528260111f, 0.99992470183914450f,
                               0.99983058179582340f, 0.99969881869620425f,
                               0.99952941750109314f, 0.99932238458834954f,
                               0.99907772775264536f };
    constexpr float CJI[8] = { 0.0f, 0.0061358846491544753f, 0.012271538285719925f,
                               0.018406729905804820f, 0.024541228522912288f,
                               0.030674803176636626f, 0.036807222941358832f,
                               0.042938256934940820f };
    float s0, c0;   // W^(8l) = e^{i*pi*lane/64}
    __sincosf(4.90873852123405e-2f * (float)lane, &s0, &c0);

    // ---- pack Z[k] = A + i*W^k*B with shuffle-sourced mirrors ----
    float Zr[8], Zi[8];
    {
        const int srcd = (64 - lane) & 63;
        float q_r = __shfl(ur[0], srcd), q_i = __shfl(ui[0], srcd);
        float v_r = __shfl(pr[0], srcd), v_i = __shfl(pi[0], srcd);
        if (lane == 0) { q_r = pr[0]; q_i = pi[0]; v_r = ur[0]; v_i = ui[0]; }
        float Ar = pr[0] + ur[0] + q_r + v_r;
        float Ai = pi[0] + ui[0] - q_i - v_i;
        float Br = pr[0] - ur[0] + q_r - v_r;
        float Bi = pi[0] - ui[0] - q_i + v_i;
        Zr[0] = Ar - (c0 * Bi + s0 * Br);
        Zi[0] = Ai + (c0 * Br - s0 * Bi);
    }
    #pragma unroll
    for (int j = 1; j < 8; ++j) {
        float q_r = __shfl_xor(ur[8 - j], 63), q_i = __shfl_xor(ui[8 - j], 63);
        float v_r = __shfl_xor(pr[8 - j], 63), v_i = __shfl_xor(pi[8 - j], 63);
        float wc = c0 * CJR[j] - s0 * CJI[j];       // W^(8l+j)
        float ws = s0 * CJR[j] + c0 * CJI[j];
        float Ar = pr[j] + ur[j] + q_r + v_r;
        float Ai = pi[j] + ui[j] - q_i - v_i;
        float Br = pr[j] - ur[j] + q_r - v_r;
        float Bi = pi[j] - ui[j] - q_i + v_i;
        Zr[j] = Ar - (wc * Bi + ws * Br);
        Zi[j] = Ai + (wc * Br - ws * Bi);
    }

    // ---- 64-pt cross-lane inverse DFT (radix-2 DIF, natural in, bit-rev out);
    //      stage twiddle via exact squaring chain: W_{h/2} = +-(W_h)^2 ----
    float ws, wc;   // W_h = e^{i*pi*(lane mod h)/h}, start h=32
    __sincosf(9.817477042468103e-2f * (float)(lane & 31), &ws, &wc);
    #pragma unroll
    for (int st = 0; st < 5; ++st) {
        const int h = 32 >> st;
        const bool hi = (lane & h) != 0;
        const float sgn  = hi ? -1.0f : 1.0f;
        const float ewc  = hi ? wc : 1.0f;
        const float ews  = hi ? ws : 0.0f;
        #pragma unroll
        for (int r = 0; r < 8; ++r) {
            float prt = __shfl_xor(Zr[r], h);
            float pit = __shfl_xor(Zi[r], h);
            float t1 = fmaf(sgn, Zr[r], prt);
            float t2 = fmaf(sgn, Zi[r], pit);
            Zr[r] = t1 * ewc - t2 * ews;
            Zi[r] = t1 * ews + t2 * ewc;
        }
        if (st < 4) {   // advance chain: W_{h/2} = (W_h)^2 * (-1)^{lane & h/2}
            const float s2 = (lane & (h >> 1)) ? -1.0f : 1.0f;
            float nwc = s2 * (wc * wc - ws * ws);
            float nws = s2 * (2.0f * wc * ws);
            wc = nwc; ws = nws;
        }
    }
    {
        const float sgn = (lane & 1) ? -1.0f : 1.0f;
        #pragma unroll
        for (int r = 0; r < 8; ++r) {
            float prt = __shfl_xor(Zr[r], 1);
            float pit = __shfl_xor(Zi[r], 1);
            Zr[r] = fmaf(sgn, Zr[r], prt);
            Zi[r] = fmaf(sgn, Zi[r], pit);
        }
    }

    // ---- per-lane twiddle e^{+2pi i * r * n1 / 512} via recurrence ----
    const int n1 = br6(lane);
    float bs, bc;   // base = e^{2pi i n1/512}
    __sincosf(1.2271846303085129e-2f * (float)n1, &bs, &bc);
    {
        float twc = bc, tws = bs;
        #pragma unroll
        for (int r = 1; r < 8; ++r) {
            float xr = Zr[r], xi = Zi[r];
            Zr[r] = xr * twc - xi * tws;
            Zi[r] = xr * tws + xi * twc;
            if (r < 7) {
                float nwc = twc * bc - tws * bs;
                float nws = twc * bs + tws * bc;
                twc = nwc; tws = nws;
            }
        }
    }

    // ---- 8-pt inverse DFT over regs (bit-rev out: reg r -> n2 = BR3[r]) ----
    dif8(Zr, Zi);

    // ---- unpack + store: X[m], m = n1 + 64*n2; y[2m]=Re*SC, y[2m+1]=Im*SC ----
    constexpr int BR3_[8] = {0, 4, 2, 6, 1, 5, 3, 7};
    const float SC = 4.8828125e-4f;   // 1/2048
    float vmin = INFINITY, vmax = -INFINITY;
    if constexpr (MODE == 1) {
        // fp16 transient: min/max tracked on the ROUNDED values for exactness
        _Float16* rrow = raw + (size_t)row * FFT_N + 2 * n1;
        #pragma unroll
        for (int r = 0; r < 8; ++r) {
            half2n h;
            h.x = (_Float16)(Zr[r] * SC);
            h.y = (_Float16)(Zi[r] * SC);
            float ra = (float)h.x, rb = (float)h.y;
            vmin = fminf(vmin, fminf(ra, rb));
            vmax = fmaxf(vmax, fmaxf(ra, rb));
            *reinterpret_cast<half2n*>(rrow + 128 * BR3_[r]) = h;
        }
    } else {
        float* orow = out + (size_t)row * FFT_N + 2 * n1;
        #pragma unroll
        for (int r = 0; r < 8; ++r) {
            float a  = Zr[r] * SC;
            float bb = Zi[r] * SC;
            vmin = fminf(vmin, fminf(a, bb));
            vmax = fmaxf(vmax, fmaxf(a, bb));
            *reinterpret_cast<float2*>(orow + 128 * BR3_[r]) = make_float2(a, bb);
        }
    }

    // ---- min/max: wave butterfly, cross-wave via LDS, one write per block ----
    #pragma unroll
    for (int off = 32; off >= 1; off >>= 1) {
        vmin = fminf(vmin, __shfl_xor(vmin, off));
        vmax = fmaxf(vmax, __shfl_xor(vmax, off));
    }
    __shared__ float smn[4], smx[4];
    if ((t & 63) == 0) { smn[wid] = vmin; smx[wid] = vmax; }
    __syncthreads();
    if (t == 0) {
        float mn = fminf(fminf(smn[0], smn[1]), fminf(smn[2], smn[3]));
        float mx = fmaxf(fmaxf(smx[0], smx[1]), fmaxf(smx[2], smx[3]));
        if (MODE == 2) {
            atomicMin(&mm[0], f2key(mn));
            atomicMax(&mm[1], f2key(mx));
        } else {
            reinterpret_cast<float2*>(partials)[blockIdx.x] = make_float2(mn, mx);
        }
    }
}

// shared partial-reduction: 4096 float2 partials -> (MN, INV) in LDS
__device__ __forceinline__ void reduce_partials(const float* __restrict__ partials,
                                                float& MN, float& INV) {
    float mn = INFINITY, mx = -INFINITY;
    #pragma unroll
    for (int it = 0; it < NBLK / 256; ++it) {
        float2 v = reinterpret_cast<const float2*>(partials)[threadIdx.x + it * 256];
        mn = fminf(mn, v.x);
        mx = fmaxf(mx, v.y);
    }
    #pragma unroll
    for (int off = 32; off >= 1; off >>= 1) {
        mn = fminf(mn, __shfl_xor(mn, off));
        mx = fmaxf(mx, __shfl_xor(mx, off));
    }
    __shared__ float smn[4], smx[4], bmm[2];
    const int wid = threadIdx.x >> 6;
    if ((threadIdx.x & 63) == 0) { smn[wid] = mn; smx[wid] = mx; }
    __syncthreads();
    if (threadIdx.x == 0) {
        bmm[0] = fminf(fminf(smn[0], smn[1]), fminf(smn[2], smn[3]));
        bmm[1] = fmaxf(fmaxf(smx[0], smx[1]), fmaxf(smx[2], smx[3]));
    }
    __syncthreads();
    MN  = bmm[0];
    INV = 1.0f / (bmm[1] - MN);
}

// fp16 path: read raw halfs (L3-hot), write normalized f32 nontemporal
__global__ __launch_bounds__(256) void normalize_h(float* __restrict__ out,
                                                   const _Float16* __restrict__ raw,
                                                   const float* __restrict__ partials,
                                                   int n8) {
    float MN, INV;
    reduce_partials(partials, MN, INV);

    const half8n* r8 = reinterpret_cast<const half8n*>(raw);
    float4n* o4 = reinterpret_cast<float4n*>(out);
    for (int i = blockIdx.x * blockDim.x + threadIdx.x; i < n8;
         i += gridDim.x * blockDim.x) {
        half8n h = r8[i];
        float4n v0, v1;
        v0.x = ((float)h[0] - MN) * INV;
        v0.y = ((float)h[1] - MN) * INV;
        v0.z = ((float)h[2] - MN) * INV;
        v0.w = ((float)h[3] - MN) * INV;
        v1.x = ((float)h[4] - MN) * INV;
        v1.y = ((float)h[5] - MN) * INV;
        v1.z = ((float)h[6] - MN) * INV;
        v1.w = ((float)h[7] - MN) * INV;
        __builtin_nontemporal_store(v0, &o4[2 * i]);
        __builtin_nontemporal_store(v1, &o4[2 * i + 1]);
    }
}

// f32 fallback: reduce partials + normalize out in place
__global__ __launch_bounds__(256) void normalize_r(float* __restrict__ out,
                                                   const float* __restrict__ partials,
                                                   int n4) {
    float MN, INV;
    reduce_partials(partials, MN, INV);

    float4n* o4 = reinterpret_cast<float4n*>(out);
    for (int i = blockIdx.x * blockDim.x + threadIdx.x; i < n4;
         i += gridDim.x * blockDim.x) {
        float4n v = o4[i];
        v.x = (v.x - MN) * INV;
        v.y = (v.y - MN) * INV;
        v.z = (v.z - MN) * INV;
        v.w = (v.w - MN) * INV;
        __builtin_nontemporal_store(v, &o4[i]);
    }
}

__global__ __launch_bounds__(256) void normalize_k(float* __restrict__ out,
                                                   const unsigned int* __restrict__ mm,
                                                   int n4) {
    const float mn  = key2f(mm[0]);
    const float inv = 1.0f / (key2f(mm[1]) - mn);
    float4n* o4 = reinterpret_cast<float4n*>(out);
    for (int i = blockIdx.x * blockDim.x + threadIdx.x; i < n4;
         i += gridDim.x * blockDim.x) {
        float4n v = o4[i];
        v.x = (v.x - mn) * inv;
        v.y = (v.y - mn) * inv;
        v.z = (v.z - mn) * inv;
        v.w = (v.w - mn) * inv;
        o4[i] = v;
    }
}

extern "C" void kernel_launch(void* const* d_in, const int* in_sizes, int n_in,
                              void* d_out, int out_size, void* d_ws, size_t ws_size,
                              hipStream_t stream) {
    const float* x = (const float*)d_in[0];
    float* out = (float*)d_out;
    const int n4 = out_size / 4;
    const int n8 = out_size / 8;
    const size_t RAWB = (size_t)out_size * sizeof(_Float16);   // 33.5 MB
    const size_t PARTB = (size_t)(2 * NBLK) * sizeof(float);   // 32 KB

    if (ws_size >= RAWB + PARTB) {
        // fp16 transient path
        _Float16* raw = (_Float16*)d_ws;
        float* partials = (float*)((char*)d_ws + RAWB);
        hipLaunchKernelGGL((hifft_rows<1>), dim3(NBLK), dim3(256), 0, stream,
                           x, out, raw, partials, nullptr);
        hipLaunchKernelGGL(normalize_h, dim3(2048), dim3(256), 0, stream,
                           out, raw, partials, n8);
    } else if (ws_size >= PARTB) {
        // proven f32 path (raw into out, normalize in place)
        float* partials = (float*)d_ws;
        hipLaunchKernelGGL((hifft_rows<0>), dim3(NBLK), dim3(256), 0, stream,
                           x, out, nullptr, partials, nullptr);
        hipLaunchKernelGGL(normalize_r, dim3(2048), dim3(256), 0, stream,
                           out, partials, n4);
    } else {
        unsigned int* mm = (unsigned int*)d_ws;
        hipLaunchKernelGGL(init_mm, dim3(1), dim3(1), 0, stream, mm);
        hipLaunchKernelGGL((hifft_rows<2>), dim3(NBLK), dim3(256), 0, stream,
                           x, out, nullptr, nullptr, mm);
        hipLaunchKernelGGL(normalize_k, dim3(2048), dim3(256), 0, stream,
                           out, mm, n4);
    }
}